// Round 1
// 203.031 us; speedup vs baseline: 1.0320x; 1.0320x over previous
//
#include <hip/hip_runtime.h>

#define HH 192
#define WW 192
#define LL (HH * WW)   // 36864
#define CC 512
#define KK 64
#define EPSF 1e-12f
typedef unsigned long long ull;
typedef unsigned int uint;
typedef unsigned short ushort;

// k3 decomposition
#define NCHUNK 192
#define CHUNKL (LL / NCHUNK)   // 192

typedef short bf16x8 __attribute__((ext_vector_type(8)));
typedef float f32x4 __attribute__((ext_vector_type(4)));

// ---------------------------------------------------------------- fp32 -> 3-way bf16 split (hi/mid/lo, truncation; exact residuals)
__device__ inline void split3(float v, ushort& h, ushort& md, ushort& lo) {
    uint b  = __float_as_uint(v);
    uint hb = b & 0xFFFF0000u;
    float r1 = v - __uint_as_float(hb);          // exact
    uint mb = __float_as_uint(r1) & 0xFFFF0000u;
    float r2 = r1 - __uint_as_float(mb);         // exact
    uint lb = __float_as_uint(r2) & 0xFFFF0000u;
    h = (ushort)(hb >> 16); md = (ushort)(mb >> 16); lo = (ushort)(lb >> 16);
}

// ---------------------------------------------------------------- k0: pre-split conv_w into fragment-ordered bf16 hi/mid/lo arrays.
// Fragment order: element W[kg*16+m][s*32 + quad*8 + j] -> ushort index ((s*4+kg)*64 + quad*16 + m)*8 + j
// so a wave's A-frag for (s,kg) is one coalesced 16B/lane load at base + ((s*4+kg)*64 + lane)*8.
__global__ __launch_bounds__(256) void k0_prep(const float* __restrict__ w,
                                               ushort* __restrict__ Whi,
                                               ushort* __restrict__ Wmid,
                                               ushort* __restrict__ Wlo,
                                               float* __restrict__ Szero) {
    int idx = blockIdx.x * 256 + threadIdx.x;   // 32768 = KK*CC
    int k = idx >> 9;
    int c = idx & 511;
    int s = c >> 5, w32 = c & 31, quad = w32 >> 3, j = w32 & 7;
    int kg = k >> 4, m = k & 15;
    int dst = (((s * 4 + kg) * 4 + quad) * 16 + m) * 8 + j;
    float v = w[idx];
    ushort h, md, lo;
    split3(v, h, md, lo);
    Whi[dst] = h; Wmid[dst] = md; Wlo[dst] = lo;
    if (blockIdx.x == 0 && threadIdx.x < 128) Szero[threadIdx.x] = 0.f;  // S[64]+rowsq[64]
}

// ---------------------------------------------------------------- k1: MFMA logits GEMM + fused norm/softmax/top2.
// 576 blocks x 128 thr = 2 independent waves. Wave owns 32 px (2 cg tiles of 16), all 64 k, c-loop 16x32.
// A (W) frags: direct global b128 loads from k0's packed arrays (L2-hot, no LDS, no cvt).
// B (x) frags: direct global->reg, 3-way bf16 split inline. 6-term MFMA => ~2^-24 rel err (fp32-equivalent)
// so the top-2 SET selection keeps the same flip-risk class as the fp32 kernel.
// No LDS, no barriers; norm/softmax/top2 reductions via cross-quad __shfl_xor(16/32).
__global__ __launch_bounds__(128) void k1_logits(const float* __restrict__ x,
                                                 const ushort* __restrict__ Whi,
                                                 const ushort* __restrict__ Wmid,
                                                 const ushort* __restrict__ Wlo,
                                                 float* __restrict__ soft,
                                                 float* __restrict__ invn,
                                                 ull* __restrict__ keep) {
    int t = threadIdx.x, lane = t & 63, wid = t >> 6;   // wid 0..1
    int m = lane & 15, quad = lane >> 4;
    int pb = blockIdx.x * 64 + wid * 32;                // wave pixel base; cg tiles at pb, pb+16

    f32x4 acc[4][2];
#pragma unroll
    for (int kg = 0; kg < 4; ++kg)
#pragma unroll
        for (int cg = 0; cg < 2; ++cg) acc[kg][cg] = (f32x4){0.f, 0.f, 0.f, 0.f};
    float ssA[2] = {0.f, 0.f};

    const float* xq = x + (size_t)(quad * 8) * LL + pb + m;   // + (s*32+j)*LL + cg*16

    for (int s = 0; s < 16; ++s) {
        // ---- A fragments: one b128/lane per (kg, array) ----
        bf16x8 Ah[4], Am[4], Al[4];
#pragma unroll
        for (int kg = 0; kg < 4; ++kg) {
            size_t off = (size_t)(((s * 4 + kg) * 64 + lane) * 8);
            Ah[kg] = *(const bf16x8*)(Whi  + off);
            Am[kg] = *(const bf16x8*)(Wmid + off);
            Al[kg] = *(const bf16x8*)(Wlo  + off);
        }
        // ---- B: direct loads (coalesced 64B segments per c-row) + ss + 3-way split ----
        float xv[2][8];
#pragma unroll
        for (int j = 0; j < 8; ++j) {
            const float* xr = xq + (size_t)j * LL;
            xv[0][j] = xr[0];
            xv[1][j] = xr[16];
        }
        xq += (size_t)32 * LL;
        bf16x8 Bh[2], Bm[2], Bl[2];
#pragma unroll
        for (int cg = 0; cg < 2; ++cg)
#pragma unroll
            for (int j = 0; j < 8; ++j) {
                float v = xv[cg][j];
                ssA[cg] = fmaf(v, v, ssA[cg]);
                ushort h, md, lo;
                split3(v, h, md, lo);
                Bh[cg][j] = (short)h; Bm[cg][j] = (short)md; Bl[cg][j] = (short)lo;
            }
        // ---- 6-term MFMA: hh + hm + mh + hl + lh + mm  (err ~2^-24) ----
#pragma unroll
        for (int kg = 0; kg < 4; ++kg)
#pragma unroll
            for (int cg = 0; cg < 2; ++cg) {
                f32x4 a = acc[kg][cg];
                a = __builtin_amdgcn_mfma_f32_16x16x32_bf16(Ah[kg], Bh[cg], a, 0, 0, 0);
                a = __builtin_amdgcn_mfma_f32_16x16x32_bf16(Ah[kg], Bm[cg], a, 0, 0, 0);
                a = __builtin_amdgcn_mfma_f32_16x16x32_bf16(Am[kg], Bh[cg], a, 0, 0, 0);
                a = __builtin_amdgcn_mfma_f32_16x16x32_bf16(Ah[kg], Bl[cg], a, 0, 0, 0);
                a = __builtin_amdgcn_mfma_f32_16x16x32_bf16(Al[kg], Bh[cg], a, 0, 0, 0);
                a = __builtin_amdgcn_mfma_f32_16x16x32_bf16(Am[kg], Bm[cg], a, 0, 0, 0);
                acc[kg][cg] = a;
            }
    }

    // ---- epilogue per cg pixel tile: D[k=kg*16+quad*4+r][px=cg*16+m] ----
#pragma unroll
    for (int cg = 0; cg < 2; ++cg) {
        float ssv = ssA[cg];
        ssv += __shfl_xor(ssv, 16);
        ssv += __shfl_xor(ssv, 32);
        float iv = 1.0f / fmaxf(sqrtf(ssv), EPSF);
        int px = pb + cg * 16 + m;
        if (quad == 0) invn[px] = iv;

        float lg[16];
        float M1 = -3.0e38f, M2 = -3.0e38f; int I1 = 0, I2 = 0;
#pragma unroll
        for (int kg = 0; kg < 4; ++kg)
#pragma unroll
            for (int r = 0; r < 4; ++r) {
                float v = acc[kg][cg][r] * iv;
                lg[kg * 4 + r] = v;
                int kk = kg * 16 + quad * 4 + r;
                if (v > M1)      { M2 = M1; I2 = I1; M1 = v; I1 = kk; }
                else if (v > M2) { M2 = v; I2 = kk; }
            }
        // cross-quad butterfly merge of (top1, top2), ties -> lower index
#pragma unroll
        for (int st = 0; st < 2; ++st) {
            int d = 16 << st;
            float a1 = __shfl_xor(M1, d); int b1 = __shfl_xor(I1, d);
            float a2 = __shfl_xor(M2, d); int b2 = __shfl_xor(I2, d);
            if (a1 > M1 || (a1 == M1 && b1 < I1)) { M2 = M1; I2 = I1; M1 = a1; I1 = b1; }
            else if (a1 > M2 || (a1 == M2 && b1 < I2)) { M2 = a1; I2 = b1; }
            if (a2 > M1 || (a2 == M1 && b2 < I1)) { M2 = M1; I2 = I1; M1 = a2; I1 = b2; }
            else if (a2 > M2 || (a2 == M2 && b2 < I2)) { M2 = a2; I2 = b2; }
        }

        float es = 0.f;
#pragma unroll
        for (int q = 0; q < 16; ++q) { float e = __expf(lg[q] - M1); lg[q] = e; es += e; }
        es += __shfl_xor(es, 16);
        es += __shfl_xor(es, 32);
        float rs = 1.0f / es;

        float4* sp = (float4*)(soft + (size_t)px * KK + quad * 4);
#pragma unroll
        for (int kg = 0; kg < 4; ++kg) {
            float4 o;
            o.x = lg[kg * 4 + 0] * rs; o.y = lg[kg * 4 + 1] * rs;
            o.z = lg[kg * 4 + 2] * rs; o.w = lg[kg * 4 + 3] * rs;
            sp[kg * 4] = o;     // soft[px*64 + kg*16 + quad*4 .. +3]
        }
        if (quad == 0) keep[px] = (1ull << I1) | (1ull << I2);
    }
}

// ---------------------------------------------------------------- k2: w2[l][k] = soft*cnt*border^4*invn[l] (in place), S[k] += unscaled
__global__ __launch_bounds__(256) void k2_weight(float* __restrict__ soft,
                                                 const ull* __restrict__ keep,
                                                 const float* __restrict__ invn,
                                                 float* __restrict__ S) {
    __shared__ float sred[4][64];
    int t = threadIdx.x, lane = t & 63, wid = t >> 6;
    int l0 = blockIdx.x * 32 + wid * 8;
    float sk = 0.f;
#pragma unroll
    for (int p = 0; p < 8; ++p) {
        int l = l0 + p;                           // wave-uniform
        int i = l / WW, j = l % WW;
        int m = min(min(i, HH - 1 - i), min(j, WW - 1 - j));
        float bm = (float)m; bm *= bm; bm *= bm;  // m^4
        int cnt = 0;
#pragma unroll
        for (int di = -1; di <= 1; ++di) {
            int ii = i + di;
            if (ii < 0 || ii >= HH) continue;
#pragma unroll
            for (int dj = -1; dj <= 1; ++dj) {
                int jj = j + dj;
                if (jj < 0 || jj >= WW) continue;
                ull nb = keep[ii * WW + jj];      // uniform -> s_load
                cnt += (int)((nb >> lane) & 1ull);
            }
        }
        float v = soft[(size_t)l * KK + lane];    // coalesced 256B
        float u = v * (float)cnt * bm;            // unscaled weight
        sk += u;
        soft[(size_t)l * KK + lane] = u * invn[l];
    }
    sred[wid][lane] = sk;
    __syncthreads();
    if (wid == 0)
        atomicAdd(&S[lane], sred[0][lane] + sred[1][lane] + sred[2][lane] + sred[3][lane]);
}

// ---------------------------------------------------------------- fp32 -> bf16 hi/lo pair converter (truncation; lo captures residual)
__device__ inline void cvt_pair(float v0, float v1, uint& hp, uint& lp) {
    uint b0 = __float_as_uint(v0), b1 = __float_as_uint(v1);
    uint h0 = b0 & 0xFFFF0000u, h1 = b1 & 0xFFFF0000u;
    float r0 = v0 - __uint_as_float(h0);
    float r1 = v1 - __uint_as_float(h1);
    hp = (h0 >> 16) | h1;
    lp = (__float_as_uint(r0) >> 16) | (__float_as_uint(r1) & 0xFFFF0000u);
}

// ---------------------------------------------------------------- k3: MFMA GEMM, bf16 3-term split
// partials[ch][k][c] = sum_{l in chunk} w2[l][k] * x[c][l]
// block 256 thr = 4 waves; tile 64k x 128c; wave c-slice 32; K-step 32 l.
__global__ __launch_bounds__(256) void k3_mfma(const float* __restrict__ w2,
                                               const float* __restrict__ x,
                                               float* __restrict__ partials) {
    __shared__ ushort wa_hi[64][40], wa_lo[64][40];     // 10 KB
    __shared__ ushort xb_hi[128][40], xb_lo[128][40];   // 20.5 KB
    int chunk = blockIdx.x;             // 0..191
    int c0 = blockIdx.y * 128;          // 0..3
    int l0 = chunk * CHUNKL;
    int t = threadIdx.x, lane = t & 63, wid = t >> 6;
    int m = lane & 15, quad = lane >> 4;

    f32x4 acc[4][2];
#pragma unroll
    for (int kg = 0; kg < 4; ++kg)
#pragma unroll
        for (int cg = 0; cg < 2; ++cg) acc[kg][cg] = (f32x4){0.f, 0.f, 0.f, 0.f};

    for (int lb = 0; lb < CHUNKL; lb += 32) {
        // ---- stage w2 (64k x 32l) -> wa[k][l], transposed, l-pairs packed as dwords ----
        {
            int k = t & 63, rg = t >> 6;            // rg 0..3
#pragma unroll
            for (int i = 0; i < 4; ++i) {
                int lp = rg + 4 * i;                // pair index 0..15
                int gl = l0 + lb + 2 * lp;
                float v0 = w2[(size_t)gl * KK + k];         // coalesced 256B rows
                float v1 = w2[(size_t)(gl + 1) * KK + k];
                uint hp, lq;
                cvt_pair(v0, v1, hp, lq);
                *(uint*)&wa_hi[k][2 * lp] = hp;
                *(uint*)&wa_lo[k][2 * lp] = lq;
            }
        }
        // ---- stage x (128c x 32l) -> xb[c][l], l-pairs packed ----
        {
            int lp = t & 15, cb = t >> 4;           // cb 0..15
            int gl = l0 + lb + 2 * lp;
#pragma unroll
            for (int i = 0; i < 8; ++i) {
                int c = cb + 16 * i;
                float v0 = x[(size_t)(c0 + c) * LL + gl];   // coalesced along l
                float v1 = x[(size_t)(c0 + c) * LL + gl + 1];
                uint hp, lq;
                cvt_pair(v0, v1, hp, lq);
                *(uint*)&xb_hi[c][2 * lp] = hp;
                *(uint*)&xb_lo[c][2 * lp] = lq;
            }
        }
        __syncthreads();
        // ---- fragments + MFMA ----
        bf16x8 Ah[4], Al[4];
#pragma unroll
        for (int kg = 0; kg < 4; ++kg) {
            Ah[kg] = *(bf16x8*)&wa_hi[kg * 16 + m][quad * 8];
            Al[kg] = *(bf16x8*)&wa_lo[kg * 16 + m][quad * 8];
        }
#pragma unroll
        for (int cg = 0; cg < 2; ++cg) {
            int crow = wid * 32 + cg * 16 + m;
            bf16x8 Bh = *(bf16x8*)&xb_hi[crow][quad * 8];
            bf16x8 Bl = *(bf16x8*)&xb_lo[crow][quad * 8];
#pragma unroll
            for (int kg = 0; kg < 4; ++kg) {
                acc[kg][cg] = __builtin_amdgcn_mfma_f32_16x16x32_bf16(Ah[kg], Bh, acc[kg][cg], 0, 0, 0);
                acc[kg][cg] = __builtin_amdgcn_mfma_f32_16x16x32_bf16(Ah[kg], Bl, acc[kg][cg], 0, 0, 0);
                acc[kg][cg] = __builtin_amdgcn_mfma_f32_16x16x32_bf16(Al[kg], Bh, acc[kg][cg], 0, 0, 0);
            }
        }
        __syncthreads();
    }
    // ---- store: D row = kg*16 + quad*4 + r, col = c0 + wid*32 + cg*16 + m ----
    float* pp = partials + (size_t)chunk * KK * CC;
#pragma unroll
    for (int kg = 0; kg < 4; ++kg)
#pragma unroll
        for (int cg = 0; cg < 2; ++cg) {
            int cout = c0 + wid * 32 + cg * 16 + m;
#pragma unroll
            for (int r = 0; r < 4; ++r) {
                int kout = kg * 16 + quad * 4 + r;
                pp[(size_t)kout * CC + cout] = acc[kg][cg][r];
            }
        }
}

// ---------------------------------------------------------------- k4a: reduce partials -> vlad, rowsq atomic
__global__ __launch_bounds__(512) void k4a_reduce(const float* __restrict__ partials,
                                                  const float* __restrict__ S,
                                                  const float* __restrict__ cent,
                                                  float* __restrict__ vlad,
                                                  float* __restrict__ rowsq) {
    __shared__ float red[512];
    int k = blockIdx.x;
    int ci = threadIdx.x & 127;
    int c = blockIdx.y * 128 + ci;
    int q = threadIdx.x >> 7;                       // 0..3
    const float* pk = partials + (size_t)q * (NCHUNK / 4) * KK * CC + (size_t)k * CC + c;
    float s0 = 0.f, s1 = 0.f, s2 = 0.f, s3 = 0.f;
    for (int ch = 0; ch < NCHUNK / 4; ch += 4) {
        s0 += pk[(size_t)(ch + 0) * KK * CC];
        s1 += pk[(size_t)(ch + 1) * KK * CC];
        s2 += pk[(size_t)(ch + 2) * KK * CC];
        s3 += pk[(size_t)(ch + 3) * KK * CC];
    }
    red[threadIdx.x] = (s0 + s1) + (s2 + s3);
    __syncthreads();
    float vsq = 0.f;
    if (q == 0) {
        float v = red[ci] + red[ci + 128] + red[ci + 256] + red[ci + 384];
        v -= S[k] * cent[k * CC + c];
        vlad[k * CC + c] = v;
        vsq = v * v;
    }
    __syncthreads();
    red[threadIdx.x] = vsq;
    __syncthreads();
    for (int off = 256; off > 0; off >>= 1) {
        if (threadIdx.x < off) red[threadIdx.x] += red[threadIdx.x + off];
        __syncthreads();
    }
    if (threadIdx.x == 0) atomicAdd(&rowsq[k], red[0]);
}

// ---------------------------------------------------------------- k4c: out = vlad * rn[k], rn computed inline from rowsq
__global__ __launch_bounds__(256) void k4c_finish(const float* __restrict__ vlad,
                                                  const float* __restrict__ rowsq,
                                                  float* __restrict__ out) {
    __shared__ float rns[64];
    int t = threadIdx.x;
    if (t < 64) {
        float tot = rowsq[t];
        float r = 1.0f / fmaxf(sqrtf(tot), EPSF);
        float contrib = tot * r * r;
#pragma unroll
        for (int off = 32; off; off >>= 1) contrib += __shfl_xor(contrib, off, 64);
        float ginv = 1.0f / fmaxf(sqrtf(contrib), EPSF);
        rns[t] = r * ginv;
    }
    __syncthreads();
    int idx4 = blockIdx.x * 256 + t;               // 8192 float4s
    int k = idx4 >> 7;
    float s = rns[k];
    float4 v = ((const float4*)vlad)[idx4];
    v.x *= s; v.y *= s; v.z *= s; v.w *= s;
    ((float4*)out)[idx4] = v;
}

// ----------------------------------------------------------------
extern "C" void kernel_launch(void* const* d_in, const int* in_sizes, int n_in,
                              void* d_out, int out_size, void* d_ws, size_t ws_size,
                              hipStream_t stream) {
    const float* x      = (const float*)d_in[0];   // (512,192,192)
    const float* conv_w = (const float*)d_in[1];   // (64,512)
    const float* cent   = (const float*)d_in[2];   // (64,512)
    float* out = (float*)d_out;                    // 32768 fp32

    float* ws    = (float*)d_ws;
    ushort* Whi  = (ushort*)ws;                     // 32768 ushorts (fragment-ordered)
    ushort* Wmid = Whi + 32768;
    ushort* Wlo  = Wmid + 32768;                    // 3 x 64KB = 49152 floats total
    float* soft  = ws + 49152;                      // KK*LL (becomes w2 in place)
    float* invn  = soft + (size_t)KK * LL;          // 36864
    float* S     = invn + LL;                       // 64
    float* rowsq = S + KK;                          // 64  (S..rowsq contiguous 128 floats)
    float* vlad  = rowsq + KK;                      // 32768
    ull*   keep  = (ull*)(vlad + 32768);            // LL u64
    float* partials = (float*)(keep + LL);          // NCHUNK*KK*CC floats (25.2 MB)

    k0_prep<<<(KK * CC) / 256, 256, 0, stream>>>(conv_w, Whi, Wmid, Wlo, S);
    k1_logits<<<LL / 64, 128, 0, stream>>>(x, Whi, Wmid, Wlo, soft, invn, keep);
    k2_weight<<<LL / 32, 256, 0, stream>>>(soft, keep, invn, S);
    k3_mfma<<<dim3(NCHUNK, 4), 256, 0, stream>>>(soft, x, partials);
    k4a_reduce<<<dim3(KK, 4), 512, 0, stream>>>(partials, S, cent, vlad, rowsq);
    k4c_finish<<<(KK * CC / 4) / 256, 256, 0, stream>>>(vlad, rowsq, out);
}

// Round 2
// 196.317 us; speedup vs baseline: 1.0673x; 1.0342x over previous
//
#include <hip/hip_runtime.h>

#define HH 192
#define WW 192
#define LL (HH * WW)   // 36864
#define CC 512
#define KK 64
#define EPSF 1e-12f
typedef unsigned long long ull;
typedef unsigned int uint;
typedef unsigned short ushort;

// k3 decomposition
#define NCHUNK 192
#define CHUNKL (LL / NCHUNK)   // 192

typedef short bf16x8 __attribute__((ext_vector_type(8)));
typedef float f32x4 __attribute__((ext_vector_type(4)));

// ---------------------------------------------------------------- fp32 -> 3-way bf16 split (hi/mid/lo, truncation; exact residuals)
__device__ inline void split3(float v, ushort& h, ushort& md, ushort& lo) {
    uint b  = __float_as_uint(v);
    uint hb = b & 0xFFFF0000u;
    float r1 = v - __uint_as_float(hb);          // exact
    uint mb = __float_as_uint(r1) & 0xFFFF0000u;
    float r2 = r1 - __uint_as_float(mb);         // exact
    uint lb = __float_as_uint(r2) & 0xFFFF0000u;
    h = (ushort)(hb >> 16); md = (ushort)(mb >> 16); lo = (ushort)(lb >> 16);
}

// ---------------------------------------------------------------- k0: pre-split conv_w into fragment-ordered bf16 hi/mid/lo arrays.
// Fragment order: element W[kg*16+m][s*32 + quad*8 + j] -> ushort index ((s*4+kg)*64 + quad*16 + m)*8 + j
// so a wave's A-frag for (s,kg) is one coalesced 16B/lane load at base + ((s*4+kg)*64 + lane)*8.
__global__ __launch_bounds__(256) void k0_prep(const float* __restrict__ w,
                                               ushort* __restrict__ Whi,
                                               ushort* __restrict__ Wmid,
                                               ushort* __restrict__ Wlo,
                                               float* __restrict__ Szero) {
    int idx = blockIdx.x * 256 + threadIdx.x;   // 32768 = KK*CC
    int k = idx >> 9;
    int c = idx & 511;
    int s = c >> 5, w32 = c & 31, quad = w32 >> 3, j = w32 & 7;
    int kg = k >> 4, m = k & 15;
    int dst = (((s * 4 + kg) * 4 + quad) * 16 + m) * 8 + j;
    float v = w[idx];
    ushort h, md, lo;
    split3(v, h, md, lo);
    Whi[dst] = h; Wmid[dst] = md; Wlo[dst] = lo;
    if (blockIdx.x == 0 && threadIdx.x < 128) Szero[threadIdx.x] = 0.f;  // S[64]+rowsq[64]
}

// ---------------------------------------------------------------- k1: MFMA logits GEMM + fused norm/softmax/top2.
// 1152 blocks x 128 thr (2 waves). Block owns 32 px; wave w contracts c-half [256w, 256w+256).
// => 2304 waves = 2.25/SIMD (was 1.1) for latency hiding; W-side L2 traffic unchanged.
// x loads register-double-buffered (prefetch s+1 during convert+MFMA of s).
// 6-term triple-bf16 MFMA => ~2^-24 rel err (fp32-equivalent) so top-2 SET selection is stable.
// Wave 1 dumps partial acc+ss to LDS ([32][64] conflict-free layout); wave 0 combines + epilogue.
__global__ __launch_bounds__(128) void k1_logits(const float* __restrict__ x,
                                                 const ushort* __restrict__ Whi,
                                                 const ushort* __restrict__ Wmid,
                                                 const ushort* __restrict__ Wlo,
                                                 float* __restrict__ soft,
                                                 float* __restrict__ invn,
                                                 ull* __restrict__ keep) {
    __shared__ float accL[32][64];   // 8 KB: wave-1 partial acc, [slot][lane]
    __shared__ float ssL[2][64];     // wave-1 partial sum-of-squares
    int t = threadIdx.x, lane = t & 63, wid = t >> 6;   // wid 0..1 = c-half
    int m = lane & 15, quad = lane >> 4;
    int pb = blockIdx.x * 32;                           // block pixel base; cg tiles at pb, pb+16

    f32x4 acc[4][2];
#pragma unroll
    for (int kg = 0; kg < 4; ++kg)
#pragma unroll
        for (int cg = 0; cg < 2; ++cg) acc[kg][cg] = (f32x4){0.f, 0.f, 0.f, 0.f};
    float ssA[2] = {0.f, 0.f};

    const float* xq = x + (size_t)(wid * 256 + quad * 8) * LL + pb + m;

    // preload s=0 x values
    float xv[2][8];
#pragma unroll
    for (int j = 0; j < 8; ++j) {
        const float* xr = xq + (size_t)j * LL;
        xv[0][j] = xr[0];
        xv[1][j] = xr[16];
    }

    for (int s = 0; s < 8; ++s) {
        int s16 = wid * 8 + s;                  // global c-chunk index 0..15
        // ---- A fragments: one b128/lane per (kg, array), L2-hot ----
        bf16x8 Ah[4], Am[4], Al[4];
#pragma unroll
        for (int kg = 0; kg < 4; ++kg) {
            size_t off = (size_t)(((s16 * 4 + kg) * 64 + lane) * 8);
            Ah[kg] = *(const bf16x8*)(Whi  + off);
            Am[kg] = *(const bf16x8*)(Wmid + off);
            Al[kg] = *(const bf16x8*)(Wlo  + off);
        }
        // ---- prefetch s+1 x values (hide latency under convert+MFMA) ----
        float xn[2][8];
        if (s < 7) {
            const float* xq2 = xq + (size_t)32 * LL;
#pragma unroll
            for (int j = 0; j < 8; ++j) {
                const float* xr = xq2 + (size_t)j * LL;
                xn[0][j] = xr[0];
                xn[1][j] = xr[16];
            }
        }
        // ---- convert current x -> B frags, accumulate ss ----
        bf16x8 Bh[2], Bm[2], Bl[2];
#pragma unroll
        for (int cg = 0; cg < 2; ++cg)
#pragma unroll
            for (int j = 0; j < 8; ++j) {
                float v = xv[cg][j];
                ssA[cg] = fmaf(v, v, ssA[cg]);
                ushort h, md, lo;
                split3(v, h, md, lo);
                Bh[cg][j] = (short)h; Bm[cg][j] = (short)md; Bl[cg][j] = (short)lo;
            }
        // ---- 6-term MFMA: hh + hm + mh + hl + lh + mm ----
#pragma unroll
        for (int kg = 0; kg < 4; ++kg)
#pragma unroll
            for (int cg = 0; cg < 2; ++cg) {
                f32x4 a = acc[kg][cg];
                a = __builtin_amdgcn_mfma_f32_16x16x32_bf16(Ah[kg], Bh[cg], a, 0, 0, 0);
                a = __builtin_amdgcn_mfma_f32_16x16x32_bf16(Ah[kg], Bm[cg], a, 0, 0, 0);
                a = __builtin_amdgcn_mfma_f32_16x16x32_bf16(Am[kg], Bh[cg], a, 0, 0, 0);
                a = __builtin_amdgcn_mfma_f32_16x16x32_bf16(Ah[kg], Bl[cg], a, 0, 0, 0);
                a = __builtin_amdgcn_mfma_f32_16x16x32_bf16(Al[kg], Bh[cg], a, 0, 0, 0);
                a = __builtin_amdgcn_mfma_f32_16x16x32_bf16(Am[kg], Bm[cg], a, 0, 0, 0);
                acc[kg][cg] = a;
            }
        if (s < 7) {
#pragma unroll
            for (int cg = 0; cg < 2; ++cg)
#pragma unroll
                for (int j = 0; j < 8; ++j) xv[cg][j] = xn[cg][j];
            xq += (size_t)32 * LL;
        }
    }

    // ---- combine c-halves through LDS ----
    if (wid == 1) {
#pragma unroll
        for (int kg = 0; kg < 4; ++kg)
#pragma unroll
            for (int cg = 0; cg < 2; ++cg)
#pragma unroll
                for (int r = 0; r < 4; ++r)
                    accL[kg * 8 + cg * 4 + r][lane] = acc[kg][cg][r];
        ssL[0][lane] = ssA[0];
        ssL[1][lane] = ssA[1];
    }
    __syncthreads();
    if (wid != 0) return;
#pragma unroll
    for (int kg = 0; kg < 4; ++kg)
#pragma unroll
        for (int cg = 0; cg < 2; ++cg)
#pragma unroll
            for (int r = 0; r < 4; ++r)
                acc[kg][cg][r] += accL[kg * 8 + cg * 4 + r][lane];
    ssA[0] += ssL[0][lane];
    ssA[1] += ssL[1][lane];

    // ---- epilogue per cg pixel tile: D[k=kg*16+quad*4+r][px=cg*16+m] ----
#pragma unroll
    for (int cg = 0; cg < 2; ++cg) {
        float ssv = ssA[cg];
        ssv += __shfl_xor(ssv, 16);
        ssv += __shfl_xor(ssv, 32);
        float iv = 1.0f / fmaxf(sqrtf(ssv), EPSF);
        int px = pb + cg * 16 + m;
        if (quad == 0) invn[px] = iv;

        float lg[16];
        float M1 = -3.0e38f, M2 = -3.0e38f; int I1 = 0, I2 = 0;
#pragma unroll
        for (int kg = 0; kg < 4; ++kg)
#pragma unroll
            for (int r = 0; r < 4; ++r) {
                float v = acc[kg][cg][r] * iv;
                lg[kg * 4 + r] = v;
                int kk = kg * 16 + quad * 4 + r;
                if (v > M1)      { M2 = M1; I2 = I1; M1 = v; I1 = kk; }
                else if (v > M2) { M2 = v; I2 = kk; }
            }
        // cross-quad butterfly merge of (top1, top2), ties -> lower index
#pragma unroll
        for (int st = 0; st < 2; ++st) {
            int d = 16 << st;
            float a1 = __shfl_xor(M1, d); int b1 = __shfl_xor(I1, d);
            float a2 = __shfl_xor(M2, d); int b2 = __shfl_xor(I2, d);
            if (a1 > M1 || (a1 == M1 && b1 < I1)) { M2 = M1; I2 = I1; M1 = a1; I1 = b1; }
            else if (a1 > M2 || (a1 == M2 && b1 < I2)) { M2 = a1; I2 = b1; }
            if (a2 > M1 || (a2 == M1 && b2 < I1)) { M2 = M1; I2 = I1; M1 = a2; I1 = b2; }
            else if (a2 > M2 || (a2 == M2 && b2 < I2)) { M2 = a2; I2 = b2; }
        }

        float es = 0.f;
#pragma unroll
        for (int q = 0; q < 16; ++q) { float e = __expf(lg[q] - M1); lg[q] = e; es += e; }
        es += __shfl_xor(es, 16);
        es += __shfl_xor(es, 32);
        float rs = 1.0f / es;

        float4* sp = (float4*)(soft + (size_t)px * KK + quad * 4);
#pragma unroll
        for (int kg = 0; kg < 4; ++kg) {
            float4 o;
            o.x = lg[kg * 4 + 0] * rs; o.y = lg[kg * 4 + 1] * rs;
            o.z = lg[kg * 4 + 2] * rs; o.w = lg[kg * 4 + 3] * rs;
            sp[kg * 4] = o;     // soft[px*64 + kg*16 + quad*4 .. +3]
        }
        if (quad == 0) keep[px] = (1ull << I1) | (1ull << I2);
    }
}

// ---------------------------------------------------------------- k2: w2[l][k] = soft*cnt*border^4*invn[l] (in place), S[k] += unscaled
__global__ __launch_bounds__(256) void k2_weight(float* __restrict__ soft,
                                                 const ull* __restrict__ keep,
                                                 const float* __restrict__ invn,
                                                 float* __restrict__ S) {
    __shared__ float sred[4][64];
    int t = threadIdx.x, lane = t & 63, wid = t >> 6;
    int l0 = blockIdx.x * 32 + wid * 8;
    float sk = 0.f;
#pragma unroll
    for (int p = 0; p < 8; ++p) {
        int l = l0 + p;                           // wave-uniform
        int i = l / WW, j = l % WW;
        int m = min(min(i, HH - 1 - i), min(j, WW - 1 - j));
        float bm = (float)m; bm *= bm; bm *= bm;  // m^4
        int cnt = 0;
#pragma unroll
        for (int di = -1; di <= 1; ++di) {
            int ii = i + di;
            if (ii < 0 || ii >= HH) continue;
#pragma unroll
            for (int dj = -1; dj <= 1; ++dj) {
                int jj = j + dj;
                if (jj < 0 || jj >= WW) continue;
                ull nb = keep[ii * WW + jj];      // uniform -> s_load
                cnt += (int)((nb >> lane) & 1ull);
            }
        }
        float v = soft[(size_t)l * KK + lane];    // coalesced 256B
        float u = v * (float)cnt * bm;            // unscaled weight
        sk += u;
        soft[(size_t)l * KK + lane] = u * invn[l];
    }
    sred[wid][lane] = sk;
    __syncthreads();
    if (wid == 0)
        atomicAdd(&S[lane], sred[0][lane] + sred[1][lane] + sred[2][lane] + sred[3][lane]);
}

// ---------------------------------------------------------------- fp32 -> bf16 hi/lo pair converter (truncation; lo captures residual)
__device__ inline void cvt_pair(float v0, float v1, uint& hp, uint& lp) {
    uint b0 = __float_as_uint(v0), b1 = __float_as_uint(v1);
    uint h0 = b0 & 0xFFFF0000u, h1 = b1 & 0xFFFF0000u;
    float r0 = v0 - __uint_as_float(h0);
    float r1 = v1 - __uint_as_float(h1);
    hp = (h0 >> 16) | h1;
    lp = (__float_as_uint(r0) >> 16) | (__float_as_uint(r1) & 0xFFFF0000u);
}

// ---------------------------------------------------------------- k3: MFMA GEMM, bf16 3-term split
// partials[ch][k][c] = sum_{l in chunk} w2[l][k] * x[c][l]
// block 256 thr = 4 waves; tile 64k x 128c; wave c-slice 32; K-step 32 l.
__global__ __launch_bounds__(256) void k3_mfma(const float* __restrict__ w2,
                                               const float* __restrict__ x,
                                               float* __restrict__ partials) {
    __shared__ ushort wa_hi[64][40], wa_lo[64][40];     // 10 KB
    __shared__ ushort xb_hi[128][40], xb_lo[128][40];   // 20.5 KB
    int chunk = blockIdx.x;             // 0..191
    int c0 = blockIdx.y * 128;          // 0..3
    int l0 = chunk * CHUNKL;
    int t = threadIdx.x, lane = t & 63, wid = t >> 6;
    int m = lane & 15, quad = lane >> 4;

    f32x4 acc[4][2];
#pragma unroll
    for (int kg = 0; kg < 4; ++kg)
#pragma unroll
        for (int cg = 0; cg < 2; ++cg) acc[kg][cg] = (f32x4){0.f, 0.f, 0.f, 0.f};

    for (int lb = 0; lb < CHUNKL; lb += 32) {
        // ---- stage w2 (64k x 32l) -> wa[k][l], transposed, l-pairs packed as dwords ----
        {
            int k = t & 63, rg = t >> 6;            // rg 0..3
#pragma unroll
            for (int i = 0; i < 4; ++i) {
                int lp = rg + 4 * i;                // pair index 0..15
                int gl = l0 + lb + 2 * lp;
                float v0 = w2[(size_t)gl * KK + k];         // coalesced 256B rows
                float v1 = w2[(size_t)(gl + 1) * KK + k];
                uint hp, lq;
                cvt_pair(v0, v1, hp, lq);
                *(uint*)&wa_hi[k][2 * lp] = hp;
                *(uint*)&wa_lo[k][2 * lp] = lq;
            }
        }
        // ---- stage x (128c x 32l) -> xb[c][l], l-pairs packed ----
        {
            int lp = t & 15, cb = t >> 4;           // cb 0..15
            int gl = l0 + lb + 2 * lp;
#pragma unroll
            for (int i = 0; i < 8; ++i) {
                int c = cb + 16 * i;
                float v0 = x[(size_t)(c0 + c) * LL + gl];   // coalesced along l
                float v1 = x[(size_t)(c0 + c) * LL + gl + 1];
                uint hp, lq;
                cvt_pair(v0, v1, hp, lq);
                *(uint*)&xb_hi[c][2 * lp] = hp;
                *(uint*)&xb_lo[c][2 * lp] = lq;
            }
        }
        __syncthreads();
        // ---- fragments + MFMA ----
        bf16x8 Ah[4], Al[4];
#pragma unroll
        for (int kg = 0; kg < 4; ++kg) {
            Ah[kg] = *(bf16x8*)&wa_hi[kg * 16 + m][quad * 8];
            Al[kg] = *(bf16x8*)&wa_lo[kg * 16 + m][quad * 8];
        }
#pragma unroll
        for (int cg = 0; cg < 2; ++cg) {
            int crow = wid * 32 + cg * 16 + m;
            bf16x8 Bh = *(bf16x8*)&xb_hi[crow][quad * 8];
            bf16x8 Bl = *(bf16x8*)&xb_lo[crow][quad * 8];
#pragma unroll
            for (int kg = 0; kg < 4; ++kg) {
                acc[kg][cg] = __builtin_amdgcn_mfma_f32_16x16x32_bf16(Ah[kg], Bh, acc[kg][cg], 0, 0, 0);
                acc[kg][cg] = __builtin_amdgcn_mfma_f32_16x16x32_bf16(Ah[kg], Bl, acc[kg][cg], 0, 0, 0);
                acc[kg][cg] = __builtin_amdgcn_mfma_f32_16x16x32_bf16(Al[kg], Bh, acc[kg][cg], 0, 0, 0);
            }
        }
        __syncthreads();
    }
    // ---- store: D row = kg*16 + quad*4 + r, col = c0 + wid*32 + cg*16 + m ----
    float* pp = partials + (size_t)chunk * KK * CC;
#pragma unroll
    for (int kg = 0; kg < 4; ++kg)
#pragma unroll
        for (int cg = 0; cg < 2; ++cg) {
            int cout = c0 + wid * 32 + cg * 16 + m;
#pragma unroll
            for (int r = 0; r < 4; ++r) {
                int kout = kg * 16 + quad * 4 + r;
                pp[(size_t)kout * CC + cout] = acc[kg][cg][r];
            }
        }
}

// ---------------------------------------------------------------- k4a: reduce partials -> vlad, rowsq atomic
__global__ __launch_bounds__(512) void k4a_reduce(const float* __restrict__ partials,
                                                  const float* __restrict__ S,
                                                  const float* __restrict__ cent,
                                                  float* __restrict__ vlad,
                                                  float* __restrict__ rowsq) {
    __shared__ float red[512];
    int k = blockIdx.x;
    int ci = threadIdx.x & 127;
    int c = blockIdx.y * 128 + ci;
    int q = threadIdx.x >> 7;                       // 0..3
    const float* pk = partials + (size_t)q * (NCHUNK / 4) * KK * CC + (size_t)k * CC + c;
    float s0 = 0.f, s1 = 0.f, s2 = 0.f, s3 = 0.f;
    for (int ch = 0; ch < NCHUNK / 4; ch += 4) {
        s0 += pk[(size_t)(ch + 0) * KK * CC];
        s1 += pk[(size_t)(ch + 1) * KK * CC];
        s2 += pk[(size_t)(ch + 2) * KK * CC];
        s3 += pk[(size_t)(ch + 3) * KK * CC];
    }
    red[threadIdx.x] = (s0 + s1) + (s2 + s3);
    __syncthreads();
    float vsq = 0.f;
    if (q == 0) {
        float v = red[ci] + red[ci + 128] + red[ci + 256] + red[ci + 384];
        v -= S[k] * cent[k * CC + c];
        vlad[k * CC + c] = v;
        vsq = v * v;
    }
    __syncthreads();
    red[threadIdx.x] = vsq;
    __syncthreads();
    for (int off = 256; off > 0; off >>= 1) {
        if (threadIdx.x < off) red[threadIdx.x] += red[threadIdx.x + off];
        __syncthreads();
    }
    if (threadIdx.x == 0) atomicAdd(&rowsq[k], red[0]);
}

// ---------------------------------------------------------------- k4c: out = vlad * rn[k], rn computed inline from rowsq
__global__ __launch_bounds__(256) void k4c_finish(const float* __restrict__ vlad,
                                                  const float* __restrict__ rowsq,
                                                  float* __restrict__ out) {
    __shared__ float rns[64];
    int t = threadIdx.x;
    if (t < 64) {
        float tot = rowsq[t];
        float r = 1.0f / fmaxf(sqrtf(tot), EPSF);
        float contrib = tot * r * r;
#pragma unroll
        for (int off = 32; off; off >>= 1) contrib += __shfl_xor(contrib, off, 64);
        float ginv = 1.0f / fmaxf(sqrtf(contrib), EPSF);
        rns[t] = r * ginv;
    }
    __syncthreads();
    int idx4 = blockIdx.x * 256 + t;               // 8192 float4s
    int k = idx4 >> 7;
    float s = rns[k];
    float4 v = ((const float4*)vlad)[idx4];
    v.x *= s; v.y *= s; v.z *= s; v.w *= s;
    ((float4*)out)[idx4] = v;
}

// ----------------------------------------------------------------
extern "C" void kernel_launch(void* const* d_in, const int* in_sizes, int n_in,
                              void* d_out, int out_size, void* d_ws, size_t ws_size,
                              hipStream_t stream) {
    const float* x      = (const float*)d_in[0];   // (512,192,192)
    const float* conv_w = (const float*)d_in[1];   // (64,512)
    const float* cent   = (const float*)d_in[2];   // (64,512)
    float* out = (float*)d_out;                    // 32768 fp32

    float* ws    = (float*)d_ws;
    ushort* Whi  = (ushort*)ws;                     // 32768 ushorts (fragment-ordered)
    ushort* Wmid = Whi + 32768;
    ushort* Wlo  = Wmid + 32768;                    // 3 x 64KB = 49152 floats total
    float* soft  = ws + 49152;                      // KK*LL (becomes w2 in place)
    float* invn  = soft + (size_t)KK * LL;          // 36864
    float* S     = invn + LL;                       // 64
    float* rowsq = S + KK;                          // 64  (S..rowsq contiguous 128 floats)
    float* vlad  = rowsq + KK;                      // 32768
    ull*   keep  = (ull*)(vlad + 32768);            // LL u64
    float* partials = (float*)(keep + LL);          // NCHUNK*KK*CC floats (25.2 MB)

    k0_prep<<<(KK * CC) / 256, 256, 0, stream>>>(conv_w, Whi, Wmid, Wlo, S);
    k1_logits<<<LL / 32, 128, 0, stream>>>(x, Whi, Wmid, Wlo, soft, invn, keep);
    k2_weight<<<LL / 32, 256, 0, stream>>>(soft, keep, invn, S);
    k3_mfma<<<dim3(NCHUNK, 4), 256, 0, stream>>>(soft, x, partials);
    k4a_reduce<<<dim3(KK, 4), 512, 0, stream>>>(partials, S, cent, vlad, rowsq);
    k4c_finish<<<(KK * CC / 4) / 256, 256, 0, stream>>>(vlad, rowsq, out);
}